// Round 13
// baseline (107.633 us; speedup 1.0000x reference)
//
#include <hip/hip_runtime.h>
#include <hip/hip_fp16.h>

#define S_LEN 8192
#define T_LEN 8192
#define D_DIM 256
#define QBLK 128
#define KVBLK 32
#define TSPLIT 8
#define NKV ((T_LEN / TSPLIT) / KVBLK)  // 32 tiles per block
#define NQT (S_LEN / QBLK)              // 64
#define KTILE_BYTES 16384               // 32 keys x 256 d x 2B (32x32 A-frag image)
#define VTILE_BYTES 16384               // 32 keys x 256 d x 2B (32x32 B-frag image)
#define RESCALE_THR 6.0f                // log2 domain
#define LOG2E 1.44269504f
// LDS: Kb 2x16KB @0 ; Vb 2x16KB @32768 -> 65536 B -> 2 blocks/CU
#define SMEM_BYTES 65536

typedef _Float16 f16x8 __attribute__((ext_vector_type(8)));
typedef float f32x16 __attribute__((ext_vector_type(16)));

struct h4 { _Float16 h[4]; };

#define GLOAD_LDS16(g, l)                                              \
    __builtin_amdgcn_global_load_lds(                                  \
        (const __attribute__((address_space(1))) void*)(g),            \
        (__attribute__((address_space(3))) void*)(l), 16, 0, 0)

#define MFMA32(a, b, c) __builtin_amdgcn_mfma_f32_32x32x16_f16(a, b, c, 0, 0, 0)

#if __has_builtin(__builtin_amdgcn_exp2f)
#define EXP2(x) __builtin_amdgcn_exp2f(x)
#else
static __device__ __forceinline__ float EXP2(float x) {
    float y;
    asm("v_exp_f32 %0, %1" : "=v"(y) : "v"(x));
    return y;
}
#endif

// ---------------- Q: fp32 -> f16 row-major, pre-scaled by log2(e) ----------------
__global__ __launch_bounds__(256) void cvt_kernel(const float* __restrict__ in,
                                                  _Float16* __restrict__ out, int n4) {
    int i = blockIdx.x * 256 + threadIdx.x;
    if (i < n4) {
        float4 v = ((const float4*)in)[i];
        h4 o;
        o.h[0] = (_Float16)(v.x * LOG2E); o.h[1] = (_Float16)(v.y * LOG2E);
        o.h[2] = (_Float16)(v.z * LOG2E); o.h[3] = (_Float16)(v.w * LOG2E);
        ((h4*)out)[i] = o;
    }
}

// ------- K -> Kimg (32x32x16 A-frag order). Granule (s,l) of tile t at
// t*16384 + s*1024 + l*16 holds K[t*32 + (l&31)][s*16 + (l>>5)*8 + j], j=0..7.
// In-kernel QK read for step s = b128 at s*1024 + lane*16: linear, conflict-free.
__global__ __launch_bounds__(256) void cvt_swz_kernel(const float* __restrict__ in,
                                                      _Float16* __restrict__ img,
                                                      int ngran) {
    int id = blockIdx.x * 256 + threadIdx.x;
    if (id >= ngran) return;
    int t = id >> 10, g = id & 1023;
    int s = g >> 6, l = g & 63;
    int row = t * 32 + (l & 31);
    int col = s * 16 + (l >> 5) * 8;
    float4 a = *(const float4*)(in + (size_t)row * D_DIM + col);
    float4 b = *(const float4*)(in + (size_t)row * D_DIM + col + 4);
    f16x8 o;
    o[0] = (_Float16)a.x; o[1] = (_Float16)a.y; o[2] = (_Float16)a.z; o[3] = (_Float16)a.w;
    o[4] = (_Float16)b.x; o[5] = (_Float16)b.y; o[6] = (_Float16)b.z; o[7] = (_Float16)b.w;
    *(f16x8*)((char*)img + (size_t)id * 16) = o;
}

// ------- V -> Vimg (32x32x16 B-frag order, kappa-permuted keys).
// Granule g (dt=g>>7, s=(g>>6)&1, l=g&63) of tile t at t*16384 + g*16 holds
// V[t*32 + kappa(s, l>>5, j)][dt*32 + (l&31)], kappa(s,hi,j)=16s+4hi+8(j>>2)+(j&3).
// kappa matches the cvt_pkrtz pack order of the S^T C-layout -> PV needs NO shuffles.
__global__ __launch_bounds__(256) void vt_swz_kernel(const float* __restrict__ V,
                                                     _Float16* __restrict__ Vimg) {
    __shared__ float tile[32][260];
    const int t = blockIdx.x;
#pragma unroll
    for (int i = 0; i < 8; ++i) {
        int idx = i * 256 + threadIdx.x;
        int kr = idx >> 6, c4 = idx & 63;
        float4 v = *(const float4*)(V + ((size_t)t * 32 + kr) * D_DIM + c4 * 4);
        tile[kr][c4 * 4 + 0] = v.x;
        tile[kr][c4 * 4 + 1] = v.y;
        tile[kr][c4 * 4 + 2] = v.z;
        tile[kr][c4 * 4 + 3] = v.w;
    }
    __syncthreads();
#pragma unroll
    for (int i = 0; i < 4; ++i) {
        int g = i * 256 + threadIdx.x;  // 1024 granules
        int dt = g >> 7, s = (g >> 6) & 1, l = g & 63;
        int hi = l >> 5, d = dt * 32 + (l & 31);
        f16x8 o;
#pragma unroll
        for (int j = 0; j < 8; ++j)
            o[j] = (_Float16)tile[16 * s + 4 * hi + 8 * (j >> 2) + (j & 3)][d];
        *(f16x8*)((char*)Vimg + (size_t)t * VTILE_BYTES + (size_t)g * 16) = o;
    }
}

// ------------- flash attention: 32x32x16 MFMA, 1-barrier/tile schedule -------------
// 4 waves x 32 q-rows. Swapped QK (A=K, B=Q) -> S^T: lane owns q=lane&31, 16 key
// regs; row-softmax = 15 fmax + 1 shfl_xor(32). cvt_pkrtz pack IS the PV A-frag
// (kappa baked into Vimg): zero shuffles. Two independent 8-MFMA QK chains.
// R12 schedule: {lgkmcnt0; vmcnt0; barrier} -> stage(kt+1) -> QK -> SM -> PV.
__global__ __launch_bounds__(256, 2) void attn_kernel(
    const _Float16* __restrict__ Qh, const _Float16* __restrict__ Kimg,
    const _Float16* __restrict__ Vimg, _Float16* __restrict__ Opart,
    float* __restrict__ ml) {
    extern __shared__ __align__(16) char smem[];
    char* sK = smem;          // 2 x 16KB
    char* sV = smem + 32768;  // 2 x 16KB
    const int tid = threadIdx.x;
    const int wave = tid >> 6, lane = tid & 63;
    const int q31 = lane & 31, hi = lane >> 5;
    const int bid = blockIdx.x;
    const int qtile = bid >> 3, split = bid & 7;  // XCD = bid % 8 = split
    const int tile0 = split * NKV;
    const int rot = ((qtile >> 5) << 4) | ((qtile & 3) << 2);  // stagger offset
    const int othr = tid * 16;
    const int lb = lane * 16;

#define TILE_AT(k) (tile0 + (((k) + rot) & (NKV - 1)))
#define STAGE_KV(k, slot)                                                          \
    {                                                                              \
        const char* Kt = (const char*)Kimg + (size_t)TILE_AT(k) * KTILE_BYTES;     \
        const char* Vt = (const char*)Vimg + (size_t)TILE_AT(k) * VTILE_BYTES;     \
        _Pragma("unroll") for (int i = 0; i < 4; ++i) {                            \
            GLOAD_LDS16(Kt + i * 4096 + othr, sK + (slot)*16384 + i * 4096 + othr); \
            GLOAD_LDS16(Vt + i * 4096 + othr, sV + (slot)*16384 + i * 4096 + othr); \
        }                                                                          \
    }

    // ---- Q B-fragments: qf[s] = Q[qrow][s*16 + hi*8 + j] ----
    f16x8 qf[16];
    {
        const size_t qrow = (size_t)qtile * QBLK + wave * 32 + q31;
#pragma unroll
        for (int s = 0; s < 16; ++s)
            qf[s] = *(const f16x8*)(Qh + qrow * D_DIM + s * 16 + hi * 8);
    }

    f32x16 acc[8];
#pragma unroll
    for (int dt = 0; dt < 8; ++dt)
#pragma unroll
        for (int r = 0; r < 16; ++r) acc[dt][r] = 0.f;
    float m = -1e30f;
    float l = 0.f;  // per-lane partial (16 of 32 keys per tile), reduced at epilogue

    // ---- prologue: stage tile 0 into slot 0 ----
    STAGE_KV(0, 0);

    for (int kt = 0; kt < NKV; ++kt) {
        asm volatile("s_waitcnt lgkmcnt(0)" ::: "memory");
        asm volatile("s_waitcnt vmcnt(0)" ::: "memory");  // stage(kt) landed (aged)
        __builtin_amdgcn_s_barrier();  // K/V(kt) visible; prior-iter reads done

        if (kt + 1 < NKV) STAGE_KV(kt + 1, (kt + 1) & 1);

        const char* sKb = sK + (kt & 1) * 16384;
        const char* sVb = sV + (kt & 1) * 16384;

        // ---- QK^T swapped: st = S^T[key=(r&3)+8(r>>2)+4hi][q=q31] ----
        f32x16 sa, sb;
#pragma unroll
        for (int r = 0; r < 16; ++r) { sa[r] = 0.f; sb[r] = 0.f; }
        __builtin_amdgcn_s_setprio(1);
#pragma unroll
        for (int s = 0; s < 16; s += 2) {
            f16x8 kfa = *(const f16x8*)(sKb + s * 1024 + lb);
            f16x8 kfb = *(const f16x8*)(sKb + (s + 1) * 1024 + lb);
            sa = MFMA32(kfa, qf[s], sa);
            sb = MFMA32(kfb, qf[s + 1], sb);
        }
        __builtin_amdgcn_s_setprio(0);
        f32x16 st = sa + sb;

        // ---- online softmax, base-2 (q-row = q31; 16 keys here, 16 in partner) ----
        float pm = st[0];
#pragma unroll
        for (int r = 1; r < 16; ++r) pm = fmaxf(pm, st[r]);
        pm = fmaxf(pm, __shfl_xor(pm, 32));
        if (__any(pm > m + RESCALE_THR)) {
            float mn = fmaxf(m, pm);
            float sc = EXP2(m - mn);
            m = mn;
            l *= sc;
            float fr[16];
#pragma unroll
            for (int r = 0; r < 16; ++r)
                fr[r] = __shfl(sc, (r & 3) + 8 * (r >> 2) + 4 * hi);
#pragma unroll
            for (int dt = 0; dt < 8; ++dt)
#pragma unroll
                for (int r = 0; r < 16; ++r) acc[dt][r] *= fr[r];
        }
        float rs = 0.f;
#pragma unroll
        for (int r = 0; r < 16; ++r) {
            float p = EXP2(st[r] - m);
            st[r] = p;
            rs += p;
        }
        l += rs;

        // ---- pack P: cvt_pk order == A-frag kappa order (no shuffles) ----
        union PU { unsigned int u[4]; f16x8 v; };
        PU pa0, pa1;
#pragma unroll
        for (int i = 0; i < 4; ++i) {
            pa0.u[i] = __builtin_bit_cast(
                unsigned int, __builtin_amdgcn_cvt_pkrtz(st[2 * i], st[2 * i + 1]));
            pa1.u[i] = __builtin_bit_cast(
                unsigned int, __builtin_amdgcn_cvt_pkrtz(st[8 + 2 * i], st[9 + 2 * i]));
        }

        // ---- PV: acc[dt] += P x V (8 dt x 2 ksteps, linear 1KB wave-reads) ----
        __builtin_amdgcn_s_setprio(1);
#pragma unroll
        for (int dt = 0; dt < 8; ++dt) {
            f16x8 vf0 = *(const f16x8*)(sVb + dt * 2048 + lb);
            f16x8 vf1 = *(const f16x8*)(sVb + dt * 2048 + 1024 + lb);
            acc[dt] = MFMA32(pa0.v, vf0, acc[dt]);
            acc[dt] = MFMA32(pa1.v, vf1, acc[dt]);
        }
        __builtin_amdgcn_s_setprio(0);
    }

    // ---- epilogue: unnormalized partial O (f16) + (m,l) ----
    _Float16* Ob = Opart + (size_t)(qtile * TSPLIT + split) * QBLK * D_DIM;
#pragma unroll
    for (int dt = 0; dt < 8; ++dt)
#pragma unroll
        for (int r = 0; r < 16; ++r) {
            int q = (r & 3) + 8 * (r >> 2) + 4 * hi;
            int row = wave * 32 + q;
            int col = dt * 32 + q31;
            Ob[(size_t)row * D_DIM + col] = (_Float16)acc[dt][r];
        }
    l += __shfl_xor(l, 32);
    if (lane < 32) {
        float* mlb = ml + (size_t)((qtile * TSPLIT + split) * QBLK) * 2;
        int row = wave * 32 + lane;
        mlb[row * 2 + 0] = m;
        mlb[row * 2 + 1] = l;
    }
}

// ---------------- combine TSPLIT partials (base-2 stats) ----------------
__global__ __launch_bounds__(256) void combine_kernel(const _Float16* __restrict__ Opart,
                                                      const float* __restrict__ ml,
                                                      float* __restrict__ out) {
    int r = blockIdx.x;
    int qtile = r >> 7, rl = r & 127;  // QBLK=128
    int d = threadIdx.x;
    float mv[TSPLIT], lv[TSPLIT];
    float M = -1e30f;
#pragma unroll
    for (int s = 0; s < TSPLIT; ++s) {
        const float* mlb = ml + (size_t)((qtile * TSPLIT + s) * QBLK + rl) * 2;
        mv[s] = mlb[0];
        lv[s] = mlb[1];
        M = fmaxf(M, mv[s]);
    }
    float num = 0.f, den = 0.f;
#pragma unroll
    for (int s = 0; s < TSPLIT; ++s) {
        float w = EXP2(mv[s] - M);
        num += w * (float)Opart[((size_t)(qtile * TSPLIT + s) * QBLK + rl) * D_DIM + d];
        den += w * lv[s];
    }
    out[(size_t)r * D_DIM + d] = num / den;
}

extern "C" void kernel_launch(void* const* d_in, const int* in_sizes, int n_in,
                              void* d_out, int out_size, void* d_ws, size_t ws_size,
                              hipStream_t stream) {
    const float* Q = (const float*)d_in[0];
    const float* K = (const float*)d_in[1];
    const float* V = (const float*)d_in[2];
    float* out = (float*)d_out;
    char* ws = (char*)d_ws;

    _Float16* Qh = (_Float16*)ws;                    // 4MB row-major f16 (x log2e)
    _Float16* Kimg = (_Float16*)(ws + (4 << 20));    // 4MB 32x32 A-frag tiles
    _Float16* Vimg = (_Float16*)(ws + (8 << 20));    // 4MB 32x32 B-frag tiles (kappa)
    _Float16* Opart = (_Float16*)(ws + (12 << 20));  // 32MB f16 partials
    float* ml = (float*)(ws + ((size_t)44 << 20));   // 512KB

    const int n4 = S_LEN * D_DIM / 4;
    const int ngran = S_LEN * D_DIM / 8;  // 262144 granules
    cvt_kernel<<<n4 / 256, 256, 0, stream>>>(Q, Qh, n4);
    cvt_swz_kernel<<<ngran / 256, 256, 0, stream>>>(K, Kimg, ngran);
    vt_swz_kernel<<<T_LEN / 32, 256, 0, stream>>>(V, Vimg);

    // 512 blocks x 256 thr, 64KB dyn LDS -> 2 blocks/CU; bid&7 = split = XCD id
    attn_kernel<<<NQT * TSPLIT, 256, SMEM_BYTES, stream>>>(Qh, Kimg, Vimg, Opart, ml);
    combine_kernel<<<S_LEN, 256, 0, stream>>>(Opart, ml, out);
}